// Round 7
// baseline (34935.300 us; speedup 1.0000x reference)
//
#include <hip/hip_runtime.h>
#include <math.h>

typedef unsigned int u32;

#define T_SEQ   2048
#define NWG     256

// ---------------- workspace layout (bytes) ----------------
#define OFF_HBUF   0            // float[2][32][512] = 131072
#define OFF_CNT    131072       // u32[8][64] (8 counters, 256B apart) = 2048
#define OFF_LASTH  133120       // float[32][512] = 65536
#define WS_NEED    198656ull

// ---------------- fallback (round-2 proven) layout ----------------
#define FB_OFF_HBUF   0
#define FB_OFF_ARRIVE 131072
#define FB_OFF_LASTH  131328

__device__ __forceinline__ float sigm(float x) { return 1.0f / (1.0f + expf(-x)); }

// ---- LLC-coherent data accessors (sc0 sc1 = bypass L1 + XCD L2) ----
// hbuf lines are ONLY ever touched via sc0sc1 ops -> never dirty in any L2.
__device__ __forceinline__ float4 ldg4s(const float* p) {
  float4 v;
  asm volatile("global_load_dwordx4 %0, %1, off sc0 sc1" : "=v"(v) : "v"(p) : "memory");
  return v;
}
__device__ __forceinline__ void stg1fs(float* p, float v) {
  asm volatile("global_store_dword %0, %1, off sc0 sc1" :: "v"(p), "v"(v) : "memory");
}

// =====================================================================
// Sequential LSTM: 256 WGs x 256 threads, plain launch (co-residency at
// 1 WG/CU proven on this HW by rounds 2/3/6).
// bg = bid&7 (4 batches), slot = bid>>3 (16 units -> 64 gate rows).
// Thread (kg = tid>>4, rg = tid&15): 4 gate rows (rr = rg*4+i), k-slice
// [kg*32, kg*32+32). W entirely in VGPRs.
// k-reduction: shfl_xor(16),(32) reduce kg within wave (lane^16 <-> kg^1,
// lane^32 <-> kg^2), then 4 wave-partials via padded LDS (conflict-free).
// Sync: ONE monotone arrive counter per bg (256B-padded). Producers
// atomicAdd(+1) after vmcnt(0)-drained sc0sc1 h stores; consumer lane 0
// polls cnt >= 32*t (monotone-barrier induction => all h_{t-1} posted).
// Watchdog: poll caps 64K iters -> sticky dead -> free-run (no hang).
// =====================================================================
__global__ void __launch_bounds__(256, 1)
lstm_seq(const int* __restrict__ x, const int* __restrict__ attn,
         const float* __restrict__ emb,
         const float* __restrict__ Wih, const float* __restrict__ Whh,
         const float* __restrict__ bih, const float* __restrict__ bhh,
         float* __restrict__ hbuf, u32* __restrict__ counters,
         float* __restrict__ lasth)
{
  __shared__ __align__(16) float wred[4 * 272];   // [wave][rg][17] padded
  __shared__ float gsc[256];
  __shared__ int s_dead;

  const int tid = threadIdx.x, bid = blockIdx.x;
  const int bg = bid & 7, slot = bid >> 3;
  const int kg = tid >> 4, rg = tid & 15;
  const int wv = tid >> 6, lane = tid & 63;

  u32* cnt = counters + bg * 64;   // 256B-padded per-bg counter

  // ---- W -> registers (64 float4 = 256 VGPR) ----
  float4 wE[4][8], wH[4][8];
#pragma unroll
  for (int i = 0; i < 4; ++i) {
    int rr = rg * 4 + i, g = rr >> 4, uu = rr & 15;
    const float* pE = Wih + (size_t)(g * 512 + slot * 16 + uu) * 512 + kg * 32;
    const float* pH = Whh + (size_t)(g * 512 + slot * 16 + uu) * 512 + kg * 32;
#pragma unroll
    for (int q = 0; q < 8; ++q) {
      wE[i][q] = *(const float4*)(pE + 4 * q);
      wH[i][q] = *(const float4*)(pH + 4 * q);
    }
  }

  // ---- lengths (partials in gsc) ----
  {
    int b = tid & 3, c = tid >> 2;   // c in [0,64)
    const int4* ap = (const int4*)(attn + (size_t)(bg * 4 + b) * 2048 + c * 32);
    int s = 0;
#pragma unroll
    for (int k = 0; k < 8; ++k) { int4 a = ap[k]; s += a.x + a.y + a.z + a.w; }
    gsc[c * 4 + b] = (float)s;
  }
  if (tid == 0) s_dead = 0;
  __syncthreads();
  int len = 0; float c_reg = 0.f;
  float bI = 0, bF = 0, bG = 0, bO = 0;
  if (tid < 64) {
    int b = tid & 3, uu = tid >> 2;
    int s = 0;
#pragma unroll
    for (int c = 0; c < 64; ++c) s += (int)gsc[c * 4 + b];
    len = s - 1; if (len < 0) len = T_SEQ - 1;
    int gu = slot * 16 + uu;
    bI = bih[gu]        + bhh[gu];
    bF = bih[512 + gu]  + bhh[512 + gu];
    bG = bih[1024 + gu] + bhh[1024 + gu];
    bO = bih[1536 + gu] + bhh[1536 + gu];
  }
  __syncthreads();   // gsc reusable

  bool dead = false;

  for (int t = 0; t < T_SEQ; ++t) {
    float acc[4][4];
#pragma unroll
    for (int i = 0; i < 4; ++i) { acc[i][0] = 0.f; acc[i][1] = 0.f; acc[i][2] = 0.f; acc[i][3] = 0.f; }

    // ---- emb half (h-independent; overlaps producer tail) ----
#pragma unroll
    for (int j = 0; j < 4; ++j) {
      int xr = x[(size_t)(bg * 4 + j) * 2048 + t];
      const float* ep = emb + (size_t)xr * 512 + kg * 32;
      float4 e[8];
#pragma unroll
      for (int q = 0; q < 8; ++q) e[q] = *(const float4*)(ep + 4 * q);
#pragma unroll
      for (int q = 0; q < 8; ++q)
#pragma unroll
        for (int i = 0; i < 4; ++i) {
          acc[i][j] += wE[i][q].x * e[q].x; acc[i][j] += wE[i][q].y * e[q].y;
          acc[i][j] += wE[i][q].z * e[q].z; acc[i][j] += wE[i][q].w * e[q].w;
        }
    }

    // ---- barrier: lane 0 polls the bg counter (1 word, 1 lane) ----
    if (tid == 0 && !dead) {
      int it = 0;
      const u32 target = (u32)(t << 5);        // 32*t
      while (__hip_atomic_load(cnt, __ATOMIC_RELAXED, __HIP_MEMORY_SCOPE_AGENT) < target) {
        if (++it > (1 << 16)) { s_dead = 1; break; }   // watchdog: no hang
        __builtin_amdgcn_s_sleep(4);
      }
    }
    __syncthreads();
    if (s_dead) dead = true;

    // ---- h half: sc0sc1 LLC loads, vmcnt(0)-drained ----
    const float* hsrc = hbuf + (((t + 1) & 1) << 14) + kg * 32;
#pragma unroll
    for (int jp = 0; jp < 2; ++jp) {
      const float* p0 = hsrc + (size_t)(bg * 4 + 2 * jp) * 512;
      const float* p1 = hsrc + (size_t)(bg * 4 + 2 * jp + 1) * 512;
      float4 hv0[8], hv1[8];
#pragma unroll
      for (int q = 0; q < 8; ++q) hv0[q] = ldg4s(p0 + 4 * q);
#pragma unroll
      for (int q = 0; q < 8; ++q) hv1[q] = ldg4s(p1 + 4 * q);
      asm volatile("s_waitcnt vmcnt(0)" ::: "memory");
      __builtin_amdgcn_sched_barrier(0);
#pragma unroll
      for (int q = 0; q < 8; ++q)
#pragma unroll
        for (int i = 0; i < 4; ++i) {
          acc[i][2 * jp]     += wH[i][q].x * hv0[q].x; acc[i][2 * jp]     += wH[i][q].y * hv0[q].y;
          acc[i][2 * jp]     += wH[i][q].z * hv0[q].z; acc[i][2 * jp]     += wH[i][q].w * hv0[q].w;
          acc[i][2 * jp + 1] += wH[i][q].x * hv1[q].x; acc[i][2 * jp + 1] += wH[i][q].y * hv1[q].y;
          acc[i][2 * jp + 1] += wH[i][q].z * hv1[q].z; acc[i][2 * jp + 1] += wH[i][q].w * hv1[q].w;
        }
    }

    // ---- k-reduction: shfl over kg within wave, LDS over 4 waves ----
#pragma unroll
    for (int i = 0; i < 4; ++i)
#pragma unroll
      for (int j = 0; j < 4; ++j) {
        float v = acc[i][j];
        v += __shfl_xor(v, 16, 64);   // kg ^ 1
        v += __shfl_xor(v, 32, 64);   // kg ^ 2
        acc[i][j] = v;
      }
    if ((lane >> 4) == 0) {           // lanes 0..15: rg == lane
#pragma unroll
      for (int i = 0; i < 4; ++i)
#pragma unroll
        for (int j = 0; j < 4; ++j)
          wred[wv * 272 + rg * 17 + i * 4 + j] = acc[i][j];
    }
    __syncthreads();
    {
      int rr = tid >> 2, j = tid & 3;
      int base = (rr >> 2) * 17 + (rr & 3) * 4 + j;
      gsc[tid] = ((wred[base] + wred[272 + base]) +
                  (wred[544 + base] + wred[816 + base]));
    }
    __syncthreads();

    // ---- activations + sc0sc1 h post (wave 0), then counter post ----
    if (tid < 64) {
      int b = tid & 3, uu = tid >> 2;
      float gi = gsc[0 * 64 + uu * 4 + b] + bI;
      float gf = gsc[1 * 64 + uu * 4 + b] + bF;
      float gg = gsc[2 * 64 + uu * 4 + b] + bG;
      float go = gsc[3 * 64 + uu * 4 + b] + bO;
      float iv = sigm(gi), fv = sigm(gf), ov = sigm(go), gv = tanhf(gg);
      c_reg = fv * c_reg + iv * gv;
      float hval = ov * tanhf(c_reg);
      int bglob = bg * 4 + b, unit = slot * 16 + uu;
      float* hd = hbuf + ((t & 1) << 14) + (bglob << 9) + unit;
      stg1fs(hd, hval);
      if (t == len) lasth[(bglob << 9) + unit] = hval;
    }
    asm volatile("s_waitcnt vmcnt(0)" ::: "memory");   // wave0's h stores at LLC
    if (tid == 0)
      __hip_atomic_fetch_add(cnt, 1u, __ATOMIC_RELAXED, __HIP_MEMORY_SCOPE_AGENT);
  }
}

// =====================================================================
// FC head
// =====================================================================
__global__ void __launch_bounds__(128)
fc_kernel(const float* __restrict__ lasth, const float* __restrict__ fcW,
          const float* __restrict__ fcb, float* __restrict__ out)
{
  int tid = threadIdx.x;
  int b = tid >> 2, n = tid & 3;
  const float4* h4 = (const float4*)(lasth + (size_t)b * 512);
  const float4* w4 = (const float4*)(fcW + (size_t)n * 512);
  float s0 = 0.f, s1 = 0.f, s2 = 0.f, s3 = 0.f;
#pragma unroll 8
  for (int k = 0; k < 128; ++k) {
    float4 a = h4[k], c = w4[k];
    s0 += a.x * c.x; s1 += a.y * c.y; s2 += a.z * c.z; s3 += a.w * c.w;
  }
  out[b * 4 + n] = fcb[n] + ((s0 + s1) + (s2 + s3));
}

// =====================================================================
// Fallback: round-2 proven persistent kernel (only if ws too small)
// =====================================================================
__device__ __forceinline__ void gl2lds16(const void* gsrc, void* ldst) {
  __builtin_amdgcn_global_load_lds(
      (const __attribute__((address_space(1))) u32*)gsrc,
      (__attribute__((address_space(3))) u32*)ldst, 16, 0, 0);
}

__global__ void __launch_bounds__(256)
lstm_persist(const int* __restrict__ xidx, const int* __restrict__ attn,
             const float* __restrict__ emb,
             const float* __restrict__ Wih, const float* __restrict__ Whh,
             const float* __restrict__ bih, const float* __restrict__ bhh,
             float* __restrict__ hbuf, float* __restrict__ lasth,
             u32* __restrict__ arrive)
{
  __shared__ __align__(16) float Wl[8][1024];
  __shared__ __align__(16) float ul[2][32][64];
  __shared__ float gsc[32][8];

  const int tid  = threadIdx.x;
  const int wg   = blockIdx.x;
  const int lane = tid & 63;
  const int wv   = tid >> 6;
  const int r    = tid & 7;
  const int bb   = tid >> 3;
  const int brl  = bb & 7;

#pragma unroll 2
  for (int i = 0; i < 8; ++i) {
    int ci = i * 256 + tid;
    int rr = ci >> 8;
    int cc = ci & 255;
    int R  = ((rr >> 1) << 9) + (wg * 2 + (rr & 1));
    const float* src = (cc < 128) ? (Wih + (size_t)R * 512 + cc * 4)
                                  : (Whh + (size_t)R * 512 + (cc - 128) * 4);
    float4 v = *(const float4*)src;
    int slot = cc ^ (rr & 7);
    *(float4*)&Wl[rr][slot * 4] = v;
  }
  float bias;
  {
    int R = ((r >> 1) << 9) + (wg * 2 + (r & 1));
    bias = bih[R] + bhh[R];
  }
  {
    int pb = tid >> 3, pc = tid & 7;
    const int4* ap = (const int4*)(attn + pb * 2048 + pc * 256);
    int s = 0;
#pragma unroll 8
    for (int k = 0; k < 64; ++k) { int4 a = ap[k]; s += a.x + a.y + a.z + a.w; }
    gsc[pb][pc] = (float)s;
  }
  __syncthreads();
  int   len_reg = 0;
  float c_reg   = 0.f;
  if (tid < 64) {
    int b2 = tid & 31;
    int s = 0;
#pragma unroll
    for (int k = 0; k < 8; ++k) s += (int)gsc[b2][k];
    len_reg = s - 1;
    if (len_reg < 0) len_reg = 2047;
  }
  __syncthreads();

  const int idx_b = 8 * wv + (lane & 7);
  int idx_cur = xidx[(size_t)idx_b * 2048];

  for (int t = 0; t < T_SEQ; ++t) {
    int idx_next = (t < T_SEQ - 1) ? xidx[(size_t)idx_b * 2048 + t + 1] : 0;
    float a0 = bias, a1 = 0.f, a2 = 0.f, a3 = 0.f;
    const float* hsrc = hbuf + (((t + 1) & 1) << 14);

    auto stageE = [&](int jt, int buf) {
#pragma unroll
      for (int q = 0; q < 2; ++q) {
        int rlq = 4 * q + (lane >> 4);
        int sc = lane & 15;
        int kc = sc ^ (rlq & 7);
        int rowg = __shfl(idx_cur, rlq, 64);
        const float* g = emb + (size_t)rowg * 512 + jt * 64 + kc * 4;
        gl2lds16(g, (void*)&ul[buf][8 * wv + 4 * q][0]);
      }
    };
    auto stageH = [&](int jt, int buf) {
#pragma unroll
      for (int q = 0; q < 2; ++q) {
        int rlq = 4 * q + (lane >> 4);
        int sc = lane & 15;
        int kc = sc ^ (rlq & 7);
        int blq = 8 * wv + rlq;
        const float* g = hsrc + (size_t)blq * 512 + jt * 64 + kc * 4;
        gl2lds16(g, (void*)&ul[buf][8 * wv + 4 * q][0]);
      }
    };
    auto computeT = [&](int jg, int buf) {
#pragma unroll
      for (int kc = 0; kc < 16; ++kc) {
        float4 uv4 = *(const float4*)&ul[buf][bb][(kc ^ brl) * 4];
        float4 wv4 = *(const float4*)&Wl[r][(((jg << 4) + kc) ^ r) * 4];
        a0 += uv4.x * wv4.x; a1 += uv4.y * wv4.y;
        a2 += uv4.z * wv4.z; a3 += uv4.w * wv4.w;
      }
    };

    stageE(0, 0);
#pragma unroll
    for (int jt = 0; jt < 8; ++jt) {
      if (jt < 7) { stageE(jt + 1, (jt + 1) & 1); asm volatile("s_waitcnt vmcnt(2)" ::: "memory"); }
      else       { asm volatile("s_waitcnt vmcnt(0)" ::: "memory"); }
      computeT(jt, jt & 1);
    }

    if (tid == 0) {
      u32 target = (u32)t << 8;
      while (__hip_atomic_load(arrive, __ATOMIC_RELAXED, __HIP_MEMORY_SCOPE_AGENT) < target)
        __builtin_amdgcn_s_sleep(2);
    }
    __syncthreads();
    __builtin_amdgcn_fence(__ATOMIC_ACQUIRE, "agent");

    stageH(0, 0);
#pragma unroll
    for (int jt = 0; jt < 8; ++jt) {
      if (jt < 7) { stageH(jt + 1, (jt + 1) & 1); asm volatile("s_waitcnt vmcnt(2)" ::: "memory"); }
      else       { asm volatile("s_waitcnt vmcnt(0)" ::: "memory"); }
      computeT(8 + jt, jt & 1);
    }

    gsc[bb][r] = a0 + a1 + a2 + a3;
    __syncthreads();
    if (tid < 64) {
      int u  = tid >> 5;
      int b2 = tid & 31;
      float gi = gsc[b2][u];
      float gf = gsc[b2][2 + u];
      float gg = gsc[b2][4 + u];
      float go = gsc[b2][6 + u];
      float iv = sigm(gi), fv = sigm(gf), ov = sigm(go);
      float gv = tanhf(gg);
      c_reg = fv * c_reg + iv * gv;
      float hv = ov * tanhf(c_reg);
      int unit = (wg << 1) + u;
      hbuf[((t & 1) << 14) + (b2 << 9) + unit] = hv;
      if (t == len_reg) lasth[(b2 << 9) + unit] = hv;
      __builtin_amdgcn_fence(__ATOMIC_RELEASE, "agent");
      if (tid == 0)
        __hip_atomic_fetch_add(arrive, 1u, __ATOMIC_RELAXED, __HIP_MEMORY_SCOPE_AGENT);
    }
    idx_cur = idx_next;
  }
}

extern "C" void kernel_launch(void* const* d_in, const int* in_sizes, int n_in,
                              void* d_out, int out_size, void* d_ws, size_t ws_size,
                              hipStream_t stream) {
  const int*   x    = (const int*)d_in[0];
  const int*   attn = (const int*)d_in[1];
  const float* emb  = (const float*)d_in[2];
  const float* Wih  = (const float*)d_in[3];
  const float* Whh  = (const float*)d_in[4];
  const float* bih  = (const float*)d_in[5];
  const float* bhh  = (const float*)d_in[6];
  const float* fcW  = (const float*)d_in[7];
  const float* fcb  = (const float*)d_in[8];
  float* out = (float*)d_out;
  char* ws = (char*)d_ws;

  if (ws_size >= WS_NEED) {
    float* hbuf  = (float*)(ws + OFF_HBUF);
    u32*   cnts  = (u32*)(ws + OFF_CNT);
    float* lasth = (float*)(ws + OFF_LASTH);

    (void)hipMemsetAsync(ws, 0, 133120, stream);   // hbuf + counters

    hipLaunchKernelGGL(lstm_seq, dim3(NWG), dim3(256), 0, stream,
                       x, attn, emb, Wih, Whh, bih, bhh, hbuf, cnts, lasth);
    hipLaunchKernelGGL(fc_kernel, dim3(1), dim3(128), 0, stream,
                       lasth, fcW, fcb, out);
  } else {
    float* hbuf   = (float*)(ws + FB_OFF_HBUF);
    u32*   arrive = (u32*)(ws + FB_OFF_ARRIVE);
    float* lasth  = (float*)(ws + FB_OFF_LASTH);
    (void)hipMemsetAsync(ws, 0, 131072 + 256, stream);
    hipLaunchKernelGGL(lstm_persist, dim3(256), dim3(256), 0, stream,
                       x, attn, emb, Wih, Whh, bih, bhh, hbuf, lasth, arrive);
    hipLaunchKernelGGL(fc_kernel, dim3(1), dim3(128), 0, stream,
                       lasth, fcW, fcb, out);
  }
}

// Round 8
// 29332.697 us; speedup vs baseline: 1.1910x; 1.1910x over previous
//
#include <hip/hip_runtime.h>
#include <math.h>

typedef unsigned int u32;

#define T_SEQ   2048
#define NWG     256

// ---------------- workspace layout (bytes) ----------------
#define OFF_HBUF   0            // float[2][32][512] = 131072
#define OFF_CNT    131072       // u32[8][64] (8 counters, 256B apart) = 2048
#define OFF_LASTH  133120       // float[32][512] = 65536
#define WS_NEED    198656ull

// ---------------- fallback (round-2 proven) layout ----------------
#define FB_OFF_HBUF   0
#define FB_OFF_ARRIVE 131072
#define FB_OFF_LASTH  131328

__device__ __forceinline__ float sigm(float x) { return 1.0f / (1.0f + expf(-x)); }

// ---- LLC-coherent data accessors (sc0 sc1 = bypass L1 + XCD L2) ----
// hbuf lines are ONLY ever touched via sc0sc1 ops -> never dirty in any L2.
__device__ __forceinline__ float4 ldg4s(const float* p) {
  float4 v;
  asm volatile("global_load_dwordx4 %0, %1, off sc0 sc1" : "=v"(v) : "v"(p) : "memory");
  return v;
}
__device__ __forceinline__ void stg1fs(float* p, float v) {
  asm volatile("global_store_dword %0, %1, off sc0 sc1" :: "v"(p), "v"(v) : "memory");
}

// =====================================================================
// Sequential LSTM v3: 256 WGs x 256 threads, plain launch (co-residency
// at 1 WG/CU proven on this HW by rounds 2/3/6/7).
// bg = bid&7 (4 batches), slot = bid>>3 (16 units -> 64 gate rows).
// Thread (kg = tid>>4, rg = tid&15): 4 gate rows (rr = rg*4+i), k-slice
// [kg*32, kg*32+32). W entirely in VGPRs.
// NEW vs r7: emb and h operands are staged UNIQUELY into LDS (2 float4
// per thread each, coalesced; h via sc0sc1) instead of each of the 16 rg
// threads redundantly loading them from the fabric (r7 FETCH showed the
// 16x redundancy = 88 GB). LDS chunk layout is kg-swizzled:
//   pos(row, kg, cc) = row*128 + kg*8 + ((cc + kg) & 7)
// so the 4 distinct-kg lanes of a wave read disjoint bank-quads and the
// 16 rg lanes broadcast (conflict-free).
// k-reduction: shfl_xor(16),(32) then padded-LDS over 4 waves (r7-proven).
// Sync: ONE monotone arrive counter per bg (256B-padded), agent atomics
// (r7-proven). h posted sc0sc1 + vmcnt(0) drain BEFORE counter post.
// Watchdog: poll caps 64K iters -> sticky dead -> free-run (no hang).
// =====================================================================
__global__ void __launch_bounds__(256, 1)
lstm_seq(const int* __restrict__ x, const int* __restrict__ attn,
         const float* __restrict__ emb,
         const float* __restrict__ Wih, const float* __restrict__ Whh,
         const float* __restrict__ bih, const float* __restrict__ bhh,
         float* __restrict__ hbuf, u32* __restrict__ counters,
         float* __restrict__ lasth)
{
  __shared__ __align__(16) float4 El[512];        // 4 rows x 128 chunks, swizzled
  __shared__ __align__(16) float4 Hl[512];        // 4 rows x 128 chunks, swizzled
  __shared__ __align__(16) float wred[4 * 272];   // [wave][rg][17] padded
  __shared__ float gsc[256];
  __shared__ int s_dead;

  const int tid = threadIdx.x, bid = blockIdx.x;
  const int bg = bid & 7, slot = bid >> 3;
  const int kg = tid >> 4, rg = tid & 15;
  const int wv = tid >> 6, lane = tid & 63;

  u32* cnt = counters + bg * 64;   // 256B-padded per-bg counter

  // ---- W -> registers (64 float4 = 256 VGPR) ----
  float4 wE[4][8], wH[4][8];
#pragma unroll
  for (int i = 0; i < 4; ++i) {
    int rr = rg * 4 + i, g = rr >> 4, uu = rr & 15;
    const float* pE = Wih + (size_t)(g * 512 + slot * 16 + uu) * 512 + kg * 32;
    const float* pH = Whh + (size_t)(g * 512 + slot * 16 + uu) * 512 + kg * 32;
#pragma unroll
    for (int q = 0; q < 8; ++q) {
      wE[i][q] = *(const float4*)(pE + 4 * q);
      wH[i][q] = *(const float4*)(pH + 4 * q);
    }
  }

  // ---- staging geometry for this thread (2 chunks of 512 total) ----
  // chunk c (0..511): row j = c>>7 (batch within bg), w = c&127 (float4 in row)
  // swizzled LDS position: j*128 + (w>>3)*8 + (((w&7) + (w>>3)) & 7)
  const int c0_ = tid, c1_ = tid + 256;
  const int j0 = c0_ >> 7, w0 = c0_ & 127;
  const int j1 = c1_ >> 7, w1 = c1_ & 127;
  const int p0 = j0 * 128 + (w0 >> 3) * 8 + (((w0 & 7) + (w0 >> 3)) & 7);
  const int p1 = j1 * 128 + (w1 >> 3) * 8 + (((w1 & 7) + (w1 >> 3)) & 7);

  // ---- lengths (partials in gsc) ----
  {
    int b = tid & 3, c = tid >> 2;   // c in [0,64)
    const int4* ap = (const int4*)(attn + (size_t)(bg * 4 + b) * 2048 + c * 32);
    int s = 0;
#pragma unroll
    for (int k = 0; k < 8; ++k) { int4 a = ap[k]; s += a.x + a.y + a.z + a.w; }
    gsc[c * 4 + b] = (float)s;
  }
  if (tid == 0) s_dead = 0;
  __syncthreads();
  int len = 0; float c_reg = 0.f;
  float bI = 0, bF = 0, bG = 0, bO = 0;
  if (tid < 64) {
    int b = tid & 3, uu = tid >> 2;
    int s = 0;
#pragma unroll
    for (int c = 0; c < 64; ++c) s += (int)gsc[c * 4 + b];
    len = s - 1; if (len < 0) len = T_SEQ - 1;
    int gu = slot * 16 + uu;
    bI = bih[gu]        + bhh[gu];
    bF = bih[512 + gu]  + bhh[512 + gu];
    bG = bih[1024 + gu] + bhh[1024 + gu];
    bO = bih[1536 + gu] + bhh[1536 + gu];
  }
  __syncthreads();   // gsc reusable

  bool dead = false;

  for (int t = 0; t < T_SEQ; ++t) {
    // ---- emb stage: 2 unique coalesced chunks/thread -> swizzled LDS ----
    {
      int xr0 = x[(size_t)(bg * 4 + j0) * 2048 + t];
      int xr1 = x[(size_t)(bg * 4 + j1) * 2048 + t];
      float4 e0 = *(const float4*)(emb + (size_t)xr0 * 512 + w0 * 4);
      float4 e1 = *(const float4*)(emb + (size_t)xr1 * 512 + w1 * 4);
      El[p0] = e0;
      El[p1] = e1;
    }
    __syncthreads();

    float acc[4][4];
#pragma unroll
    for (int i = 0; i < 4; ++i) { acc[i][0] = 0.f; acc[i][1] = 0.f; acc[i][2] = 0.f; acc[i][3] = 0.f; }

    // ---- emb FMA from LDS (h-independent; overlaps producer tail) ----
#pragma unroll
    for (int j = 0; j < 4; ++j)
#pragma unroll
      for (int q = 0; q < 8; ++q) {
        float4 ev = El[j * 128 + kg * 8 + ((q + kg) & 7)];
#pragma unroll
        for (int i = 0; i < 4; ++i) {
          acc[i][j] += wE[i][q].x * ev.x; acc[i][j] += wE[i][q].y * ev.y;
          acc[i][j] += wE[i][q].z * ev.z; acc[i][j] += wE[i][q].w * ev.w;
        }
      }

    // ---- barrier: lane 0 polls the bg counter (1 word, 1 lane) ----
    if (tid == 0 && !dead) {
      int it = 0;
      const u32 target = (u32)(t << 5);        // 32*t
      while (__hip_atomic_load(cnt, __ATOMIC_RELAXED, __HIP_MEMORY_SCOPE_AGENT) < target) {
        if (++it > (1 << 16)) { s_dead = 1; break; }   // watchdog: no hang
        __builtin_amdgcn_s_sleep(4);
      }
    }
    __syncthreads();
    if (s_dead) dead = true;

    // ---- h stage: 2 unique coalesced sc0sc1 chunks/thread -> LDS ----
    {
      const float* hsrc = hbuf + (((t + 1) & 1) << 14) + (size_t)(bg * 4) * 512;
      float4 h0 = ldg4s(hsrc + (size_t)j0 * 512 + w0 * 4);
      float4 h1 = ldg4s(hsrc + (size_t)j1 * 512 + w1 * 4);
      asm volatile("s_waitcnt vmcnt(0)" ::: "memory");
      __builtin_amdgcn_sched_barrier(0);
      Hl[p0] = h0;
      Hl[p1] = h1;
    }
    __syncthreads();

    // ---- h FMA from LDS ----
#pragma unroll
    for (int j = 0; j < 4; ++j)
#pragma unroll
      for (int q = 0; q < 8; ++q) {
        float4 hv = Hl[j * 128 + kg * 8 + ((q + kg) & 7)];
#pragma unroll
        for (int i = 0; i < 4; ++i) {
          acc[i][j] += wH[i][q].x * hv.x; acc[i][j] += wH[i][q].y * hv.y;
          acc[i][j] += wH[i][q].z * hv.z; acc[i][j] += wH[i][q].w * hv.w;
        }
      }

    // ---- k-reduction: shfl over kg within wave, LDS over 4 waves ----
#pragma unroll
    for (int i = 0; i < 4; ++i)
#pragma unroll
      for (int j = 0; j < 4; ++j) {
        float v = acc[i][j];
        v += __shfl_xor(v, 16, 64);   // kg ^ 1
        v += __shfl_xor(v, 32, 64);   // kg ^ 2
        acc[i][j] = v;
      }
    if ((lane >> 4) == 0) {           // lanes 0..15: rg == lane
#pragma unroll
      for (int i = 0; i < 4; ++i)
#pragma unroll
        for (int j = 0; j < 4; ++j)
          wred[wv * 272 + rg * 17 + i * 4 + j] = acc[i][j];
    }
    __syncthreads();
    {
      int rr = tid >> 2, j = tid & 3;
      int base = (rr >> 2) * 17 + (rr & 3) * 4 + j;
      gsc[tid] = ((wred[base] + wred[272 + base]) +
                  (wred[544 + base] + wred[816 + base]));
    }
    __syncthreads();

    // ---- activations + sc0sc1 h post (wave 0), then counter post ----
    if (tid < 64) {
      int b = tid & 3, uu = tid >> 2;
      float gi = gsc[0 * 64 + uu * 4 + b] + bI;
      float gf = gsc[1 * 64 + uu * 4 + b] + bF;
      float gg = gsc[2 * 64 + uu * 4 + b] + bG;
      float go = gsc[3 * 64 + uu * 4 + b] + bO;
      float iv = sigm(gi), fv = sigm(gf), ov = sigm(go), gv = tanhf(gg);
      c_reg = fv * c_reg + iv * gv;
      float hval = ov * tanhf(c_reg);
      int bglob = bg * 4 + b, unit = slot * 16 + uu;
      float* hd = hbuf + ((t & 1) << 14) + (bglob << 9) + unit;
      stg1fs(hd, hval);
      if (t == len) lasth[(bglob << 9) + unit] = hval;
    }
    asm volatile("s_waitcnt vmcnt(0)" ::: "memory");   // wave0's h stores at LLC
    if (tid == 0)
      __hip_atomic_fetch_add(cnt, 1u, __ATOMIC_RELAXED, __HIP_MEMORY_SCOPE_AGENT);
  }
}

// =====================================================================
// FC head
// =====================================================================
__global__ void __launch_bounds__(128)
fc_kernel(const float* __restrict__ lasth, const float* __restrict__ fcW,
          const float* __restrict__ fcb, float* __restrict__ out)
{
  int tid = threadIdx.x;
  int b = tid >> 2, n = tid & 3;
  const float4* h4 = (const float4*)(lasth + (size_t)b * 512);
  const float4* w4 = (const float4*)(fcW + (size_t)n * 512);
  float s0 = 0.f, s1 = 0.f, s2 = 0.f, s3 = 0.f;
#pragma unroll 8
  for (int k = 0; k < 128; ++k) {
    float4 a = h4[k], c = w4[k];
    s0 += a.x * c.x; s1 += a.y * c.y; s2 += a.z * c.z; s3 += a.w * c.w;
  }
  out[b * 4 + n] = fcb[n] + ((s0 + s1) + (s2 + s3));
}

// =====================================================================
// Fallback: round-2 proven persistent kernel (only if ws too small)
// =====================================================================
__device__ __forceinline__ void gl2lds16(const void* gsrc, void* ldst) {
  __builtin_amdgcn_global_load_lds(
      (const __attribute__((address_space(1))) u32*)gsrc,
      (__attribute__((address_space(3))) u32*)ldst, 16, 0, 0);
}

__global__ void __launch_bounds__(256)
lstm_persist(const int* __restrict__ xidx, const int* __restrict__ attn,
             const float* __restrict__ emb,
             const float* __restrict__ Wih, const float* __restrict__ Whh,
             const float* __restrict__ bih, const float* __restrict__ bhh,
             float* __restrict__ hbuf, float* __restrict__ lasth,
             u32* __restrict__ arrive)
{
  __shared__ __align__(16) float Wl[8][1024];
  __shared__ __align__(16) float ul[2][32][64];
  __shared__ float gsc[32][8];

  const int tid  = threadIdx.x;
  const int wg   = blockIdx.x;
  const int lane = tid & 63;
  const int wv   = tid >> 6;
  const int r    = tid & 7;
  const int bb   = tid >> 3;
  const int brl  = bb & 7;

#pragma unroll 2
  for (int i = 0; i < 8; ++i) {
    int ci = i * 256 + tid;
    int rr = ci >> 8;
    int cc = ci & 255;
    int R  = ((rr >> 1) << 9) + (wg * 2 + (rr & 1));
    const float* src = (cc < 128) ? (Wih + (size_t)R * 512 + cc * 4)
                                  : (Whh + (size_t)R * 512 + (cc - 128) * 4);
    float4 v = *(const float4*)src;
    int slot = cc ^ (rr & 7);
    *(float4*)&Wl[rr][slot * 4] = v;
  }
  float bias;
  {
    int R = ((r >> 1) << 9) + (wg * 2 + (r & 1));
    bias = bih[R] + bhh[R];
  }
  {
    int pb = tid >> 3, pc = tid & 7;
    const int4* ap = (const int4*)(attn + pb * 2048 + pc * 256);
    int s = 0;
#pragma unroll 8
    for (int k = 0; k < 64; ++k) { int4 a = ap[k]; s += a.x + a.y + a.z + a.w; }
    gsc[pb][pc] = (float)s;
  }
  __syncthreads();
  int   len_reg = 0;
  float c_reg   = 0.f;
  if (tid < 64) {
    int b2 = tid & 31;
    int s = 0;
#pragma unroll
    for (int k = 0; k < 8; ++k) s += (int)gsc[b2][k];
    len_reg = s - 1;
    if (len_reg < 0) len_reg = 2047;
  }
  __syncthreads();

  const int idx_b = 8 * wv + (lane & 7);
  int idx_cur = xidx[(size_t)idx_b * 2048];

  for (int t = 0; t < T_SEQ; ++t) {
    int idx_next = (t < T_SEQ - 1) ? xidx[(size_t)idx_b * 2048 + t + 1] : 0;
    float a0 = bias, a1 = 0.f, a2 = 0.f, a3 = 0.f;
    const float* hsrc = hbuf + (((t + 1) & 1) << 14);

    auto stageE = [&](int jt, int buf) {
#pragma unroll
      for (int q = 0; q < 2; ++q) {
        int rlq = 4 * q + (lane >> 4);
        int sc = lane & 15;
        int kc = sc ^ (rlq & 7);
        int rowg = __shfl(idx_cur, rlq, 64);
        const float* g = emb + (size_t)rowg * 512 + jt * 64 + kc * 4;
        gl2lds16(g, (void*)&ul[buf][8 * wv + 4 * q][0]);
      }
    };
    auto stageH = [&](int jt, int buf) {
#pragma unroll
      for (int q = 0; q < 2; ++q) {
        int rlq = 4 * q + (lane >> 4);
        int sc = lane & 15;
        int kc = sc ^ (rlq & 7);
        int blq = 8 * wv + rlq;
        const float* g = hsrc + (size_t)blq * 512 + jt * 64 + kc * 4;
        gl2lds16(g, (void*)&ul[buf][8 * wv + 4 * q][0]);
      }
    };
    auto computeT = [&](int jg, int buf) {
#pragma unroll
      for (int kc = 0; kc < 16; ++kc) {
        float4 uv4 = *(const float4*)&ul[buf][bb][(kc ^ brl) * 4];
        float4 wv4 = *(const float4*)&Wl[r][(((jg << 4) + kc) ^ r) * 4];
        a0 += uv4.x * wv4.x; a1 += uv4.y * wv4.y;
        a2 += uv4.z * wv4.z; a3 += uv4.w * wv4.w;
      }
    };

    stageE(0, 0);
#pragma unroll
    for (int jt = 0; jt < 8; ++jt) {
      if (jt < 7) { stageE(jt + 1, (jt + 1) & 1); asm volatile("s_waitcnt vmcnt(2)" ::: "memory"); }
      else       { asm volatile("s_waitcnt vmcnt(0)" ::: "memory"); }
      computeT(jt, jt & 1);
    }

    if (tid == 0) {
      u32 target = (u32)t << 8;
      while (__hip_atomic_load(arrive, __ATOMIC_RELAXED, __HIP_MEMORY_SCOPE_AGENT) < target)
        __builtin_amdgcn_s_sleep(2);
    }
    __syncthreads();
    __builtin_amdgcn_fence(__ATOMIC_ACQUIRE, "agent");

    stageH(0, 0);
#pragma unroll
    for (int jt = 0; jt < 8; ++jt) {
      if (jt < 7) { stageH(jt + 1, (jt + 1) & 1); asm volatile("s_waitcnt vmcnt(2)" ::: "memory"); }
      else       { asm volatile("s_waitcnt vmcnt(0)" ::: "memory"); }
      computeT(8 + jt, jt & 1);
    }

    gsc[bb][r] = a0 + a1 + a2 + a3;
    __syncthreads();
    if (tid < 64) {
      int u  = tid >> 5;
      int b2 = tid & 31;
      float gi = gsc[b2][u];
      float gf = gsc[b2][2 + u];
      float gg = gsc[b2][4 + u];
      float go = gsc[b2][6 + u];
      float iv = sigm(gi), fv = sigm(gf), ov = sigm(go);
      float gv = tanhf(gg);
      c_reg = fv * c_reg + iv * gv;
      float hv = ov * tanhf(c_reg);
      int unit = (wg << 1) + u;
      hbuf[((t & 1) << 14) + (b2 << 9) + unit] = hv;
      if (t == len_reg) lasth[(b2 << 9) + unit] = hv;
      __builtin_amdgcn_fence(__ATOMIC_RELEASE, "agent");
      if (tid == 0)
        __hip_atomic_fetch_add(arrive, 1u, __ATOMIC_RELAXED, __HIP_MEMORY_SCOPE_AGENT);
    }
    idx_cur = idx_next;
  }
}

extern "C" void kernel_launch(void* const* d_in, const int* in_sizes, int n_in,
                              void* d_out, int out_size, void* d_ws, size_t ws_size,
                              hipStream_t stream) {
  const int*   x    = (const int*)d_in[0];
  const int*   attn = (const int*)d_in[1];
  const float* emb  = (const float*)d_in[2];
  const float* Wih  = (const float*)d_in[3];
  const float* Whh  = (const float*)d_in[4];
  const float* bih  = (const float*)d_in[5];
  const float* bhh  = (const float*)d_in[6];
  const float* fcW  = (const float*)d_in[7];
  const float* fcb  = (const float*)d_in[8];
  float* out = (float*)d_out;
  char* ws = (char*)d_ws;

  if (ws_size >= WS_NEED) {
    float* hbuf  = (float*)(ws + OFF_HBUF);
    u32*   cnts  = (u32*)(ws + OFF_CNT);
    float* lasth = (float*)(ws + OFF_LASTH);

    (void)hipMemsetAsync(ws, 0, 133120, stream);   // hbuf + counters

    hipLaunchKernelGGL(lstm_seq, dim3(NWG), dim3(256), 0, stream,
                       x, attn, emb, Wih, Whh, bih, bhh, hbuf, cnts, lasth);
    hipLaunchKernelGGL(fc_kernel, dim3(1), dim3(128), 0, stream,
                       lasth, fcW, fcb, out);
  } else {
    float* hbuf   = (float*)(ws + FB_OFF_HBUF);
    u32*   arrive = (u32*)(ws + FB_OFF_ARRIVE);
    float* lasth  = (float*)(ws + FB_OFF_LASTH);
    (void)hipMemsetAsync(ws, 0, 131072 + 256, stream);
    hipLaunchKernelGGL(lstm_persist, dim3(256), dim3(256), 0, stream,
                       x, attn, emb, Wih, Whh, bih, bhh, hbuf, lasth, arrive);
    hipLaunchKernelGGL(fc_kernel, dim3(1), dim3(128), 0, stream,
                       lasth, fcW, fcb, out);
  }
}